// Round 5
// baseline (105.696 us; speedup 1.0000x reference)
//
#include <hip/hip_runtime.h>
#include <hip/hip_bf16.h>

#define NB 8
#define BIN 512
#define BOUT 512
#define BATCH 8192
#define DIM 4096   // NB*BIN

typedef __attribute__((ext_vector_type(8))) short bf16x8;
typedef __attribute__((ext_vector_type(4))) float f32x4;

#define SWZ(r) (((r) & 7) << 4)

__device__ __forceinline__ unsigned short f2bf_rne(float f) {
    unsigned u = __builtin_bit_cast(unsigned, f);
    unsigned r = (u + 0x7FFFu + ((u >> 16) & 1u)) >> 16;
    return (unsigned short)r;
}

__device__ __forceinline__ unsigned long long pack4(f32x4 f) {
    return (unsigned long long)f2bf_rne(f.x)
         | ((unsigned long long)f2bf_rne(f.y) << 16)
         | ((unsigned long long)f2bf_rne(f.z) << 32)
         | ((unsigned long long)f2bf_rne(f.w) << 48);
}

// ---------------- weight pack: f32 [nb][512][512] -> per-(nb,wn) bf16 fragment streams ----------------
// Stream layout: frag (nb, wn, kidx 0..15, n 0..7): 64 lanes x 16B, contiguous 1KB.
// In-kernel fragment load: stream + ((kidx*8+n)*512 + lane*8) ushorts.
__global__ void pack_w(const float* __restrict__ W, unsigned short* __restrict__ pk) {
    int gid = blockIdx.x * 256 + threadIdx.x;        // 262144 total
    int lane = gid & 63;
    int n    = (gid >> 6) & 7;
    int kidx = (gid >> 9) & 15;
    int wn   = (gid >> 13) & 3;
    int nb   = gid >> 15;
    int row  = wn * 128 + n * 16 + (lane & 15);      // 0..511 within block
    int col  = kidx * 32 + (lane >> 4) * 8;          // 0..511
    const float* s = W + ((size_t)nb * BOUT + row) * BIN + col;
    f32x4 a = *(const f32x4*)s;
    f32x4 b = *(const f32x4*)(s + 4);
    unsigned long long* d = (unsigned long long*)(pk + (size_t)gid * 8);
    d[0] = pack4(a);
    d[1] = pack4(b);
}

// ---------------- fused 2-layer block-diag MLP ----------------
// wg: 64 batch rows x one full diagonal block (512 cols), both layers.
// 256 threads = 4 waves (1x4 over cols); per wave 64x128 out = 4x8 fp32x4 acc.
// W never touches LDS: register-double-buffered fragment-stream loads (q0/q1).
// As (x tile) double-buffered in LDS, ONE raw barrier per K-step, counted waits
// (lgkmcnt(0) only) so global prefetch stays in flight across barriers.
// LDS pool 64 KB (As dbuf aliased under Hs) -> 2 independent blocks/CU.
__global__ __launch_bounds__(256, 2)
void fused_mlp(const float* __restrict__ X,
               const unsigned short* __restrict__ PK1,
               const float* __restrict__ B1,
               const unsigned short* __restrict__ PK2,
               const float* __restrict__ B2,
               float* __restrict__ Out)
{
    __shared__ __align__(16) unsigned char pool[65536];
    unsigned char* As = pool;                 // [2][64 rows][128B] = 16 KB (phase 1)
    unsigned char* Hs = pool;                 // [64 rows][1024B]  = 64 KB (phase 2, aliases As)

    const int bid = blockIdx.x;
    const int nb = bid & 7;       // XCD pin: keeps this block's W streams in one L2
    const int mt = bid >> 3;      // 0..127

    const int t = threadIdx.x;
    const int lane = t & 63;
    const int wn = t >> 6;        // 0..3
    const int l15 = lane & 15;
    const int lhi = lane >> 4;

    const int row0 = mt * 64;
    const int wc0  = nb * 512;

    const int sr = t >> 2;        // staging row 0..63
    const int sc = (t & 3) * 16;  // staging col (f32) 0,16,32,48

    const unsigned short* s1 = PK1 + (size_t)(nb * 4 + wn) * 65536;
    const unsigned short* s2 = PK2 + (size_t)(nb * 4 + wn) * 65536;

    f32x4 acc[4][8];
    #pragma unroll
    for (int m = 0; m < 4; m++)
        #pragma unroll
        for (int n = 0; n < 8; n++)
            acc[m][n] = (f32x4)(0.f);

    f32x4 xp[4];
    bf16x8 q0[8], q1[8];

#define LOAD_XP(KT) { \
    _Pragma("unroll") for (int j = 0; j < 4; j++) \
        xp[j] = *(const f32x4*)(X + (size_t)(row0 + sr) * DIM + wc0 + (KT) * 64 + sc + j * 4); }

#define STAGE_AS(BUF) { \
    _Pragma("unroll") for (int h2 = 0; h2 < 2; h2++) { \
        bf16x8 v; \
        ((unsigned long long*)&v)[0] = pack4(xp[h2 * 2 + 0]); \
        ((unsigned long long*)&v)[1] = pack4(xp[h2 * 2 + 1]); \
        *(bf16x8*)(As + (BUF) * 8192 + sr * 128 + (((sc + 8 * h2) * 2) ^ SWZ(sr))) = v; } }

#define LOADQ(Q, S, KIDX) { \
    _Pragma("unroll") for (int n = 0; n < 8; n++) \
        Q[n] = *(const bf16x8*)((S) + ((KIDX) * 8 + n) * 512 + lane * 8); }

#define MFMA32(Q, AF) \
    __builtin_amdgcn_s_setprio(1); \
    _Pragma("unroll") for (int m = 0; m < 4; m++) \
        _Pragma("unroll") for (int n = 0; n < 8; n++) \
            acc[m][n] = __builtin_amdgcn_mfma_f32_16x16x32_bf16(AF[m], Q[n], acc[m][n], 0, 0, 0); \
    __builtin_amdgcn_s_setprio(0);

#define P1STEP(Q, BUF, KS) { \
    bf16x8 af[4]; \
    const int cb_ = ((KS) * 32 + lhi * 8) * 2; \
    _Pragma("unroll") for (int m = 0; m < 4; m++) { \
        const int r_ = m * 16 + l15; \
        af[m] = *(const bf16x8*)(As + (BUF) * 8192 + r_ * 128 + (cb_ ^ SWZ(r_))); } \
    MFMA32(Q, af) }

#define P2STEP(Q, KIDX) { \
    bf16x8 af[4]; \
    const int cb_ = ((KIDX) * 32 + lhi * 8) * 2; \
    _Pragma("unroll") for (int m = 0; m < 4; m++) { \
        const int r_ = m * 16 + l15; \
        af[m] = *(const bf16x8*)(Hs + r_ * 1024 + (cb_ ^ SWZ(r_))); } \
    MFMA32(Q, af) }

#define BAR() { \
    asm volatile("s_waitcnt lgkmcnt(0)" ::: "memory"); \
    __builtin_amdgcn_s_barrier(); \
    __builtin_amdgcn_sched_barrier(0); }

    // ---- prologue ----
    LOAD_XP(0);
    STAGE_AS(0);
    LOAD_XP(1);
    LOADQ(q0, s1, 0);
    BAR();

    // ================= phase 1: h = relu(x @ W1^T + b1) =================
    #pragma unroll
    for (int kt = 0; kt < 8; kt++) {
        const int buf = kt & 1;
        LOADQ(q1, s1, 2 * kt + 1);          // prefetch next W1 frag set
        P1STEP(q0, buf, 0);
        if (kt < 7) { STAGE_AS(buf ^ 1); }  // stage x tile for kt+1 (other buffer)
        if (kt < 6) { LOAD_XP(kt + 2); }    // prefetch x for kt+2
        if (kt < 7) { LOADQ(q0, s1, 2 * kt + 2); }
        else        { LOADQ(q0, s2, 0); }   // seed phase-2 W2 prefetch
        P1STEP(q1, buf, 1);
        BAR();                              // writes visible; global loads stay in flight
    }

    // ---- h = relu(acc + b1) -> Hs (aliases As; kt=7 BAR guaranteed As reads done) ----
    #pragma unroll
    for (int n = 0; n < 8; n++) {
        const int c = wn * 128 + n * 16 + l15;
        const float bv = B1[wc0 + c];
        #pragma unroll
        for (int m = 0; m < 4; m++) {
            #pragma unroll
            for (int rr = 0; rr < 4; rr++) {
                float v = acc[m][n][rr] + bv;
                v = v > 0.f ? v : 0.f;
                const int r = m * 16 + lhi * 4 + rr;
                *(unsigned short*)(Hs + r * 1024 + ((c * 2) ^ SWZ(r))) = f2bf_rne(v);
            }
        }
    }
    BAR();

    #pragma unroll
    for (int m = 0; m < 4; m++)
        #pragma unroll
        for (int n = 0; n < 8; n++)
            acc[m][n] = (f32x4)(0.f);

    // ================= phase 2: out = relu(h @ W2^T + b2), no barriers =================
    #pragma unroll
    for (int kk = 0; kk < 8; kk++) {
        LOADQ(q1, s2, 2 * kk + 1);
        P2STEP(q0, 2 * kk);
        if (kk < 7) { LOADQ(q0, s2, 2 * kk + 2); }
        P2STEP(q1, 2 * kk + 1);
    }

    // ---- epilogue: out = relu(acc + b2), f32 ----
    #pragma unroll
    for (int n = 0; n < 8; n++) {
        const int c = wc0 + wn * 128 + n * 16 + l15;
        const float bv = B2[c];
        #pragma unroll
        for (int m = 0; m < 4; m++) {
            const int rb = row0 + m * 16 + lhi * 4;
            #pragma unroll
            for (int rr = 0; rr < 4; rr++) {
                float v = acc[m][n][rr] + bv;
                Out[(size_t)(rb + rr) * DIM + c] = v > 0.f ? v : 0.f;
            }
        }
    }

#undef LOAD_XP
#undef STAGE_AS
#undef LOADQ
#undef MFMA32
#undef P1STEP
#undef P2STEP
#undef BAR
}

extern "C" void kernel_launch(void* const* d_in, const int* in_sizes, int n_in,
                              void* d_out, int out_size, void* d_ws, size_t ws_size,
                              hipStream_t stream) {
    const float* x  = (const float*)d_in[0];
    const float* W1 = (const float*)d_in[1];
    const float* b1 = (const float*)d_in[2];
    const float* W2 = (const float*)d_in[3];
    const float* b2 = (const float*)d_in[4];
    float* out = (float*)d_out;

    char* ws = (char*)d_ws;
    unsigned short* PK1 = (unsigned short*)ws;                 // 4 MB
    unsigned short* PK2 = (unsigned short*)(ws + (4u << 20));  // 4 MB

    pack_w<<<1024, 256, 0, stream>>>(W1, PK1);
    pack_w<<<1024, 256, 0, stream>>>(W2, PK2);

    const int GRID = NB * (BATCH / 64);     // 1024
    fused_mlp<<<GRID, 256, 0, stream>>>(x, PK1, b1, PK2, b2, out);
}

// Round 6
// 104.854 us; speedup vs baseline: 1.0080x; 1.0080x over previous
//
#include <hip/hip_runtime.h>
#include <hip/hip_bf16.h>

#define NB 8
#define BIN 512
#define BOUT 512
#define BATCH 8192
#define DIM 4096   // NB*BIN

typedef __attribute__((ext_vector_type(8))) short bf16x8;
typedef __attribute__((ext_vector_type(4))) float f32x4;

#define SWZ(r) (((r) & 7) << 4)

__device__ __forceinline__ unsigned short f2bf_rne(float f) {
    unsigned u = __builtin_bit_cast(unsigned, f);
    unsigned r = (u + 0x7FFFu + ((u >> 16) & 1u)) >> 16;
    return (unsigned short)r;
}

__device__ __forceinline__ unsigned long long pack4(f32x4 f) {
    return (unsigned long long)f2bf_rne(f.x)
         | ((unsigned long long)f2bf_rne(f.y) << 16)
         | ((unsigned long long)f2bf_rne(f.z) << 32)
         | ((unsigned long long)f2bf_rne(f.w) << 48);
}

// ---------------- weight pack: f32 [nb][512][512] -> per-(nb,wn) bf16 fragment streams ----------------
// Stream layout: frag (nb, wn, kidx 0..15, n 0..7): 64 lanes x 16B, contiguous 1KB.
// In-kernel fragment load: stream + ((kidx*8+n)*512 + lane*8) ushorts.
__global__ void pack_w(const float* __restrict__ W, unsigned short* __restrict__ pk) {
    int gid = blockIdx.x * 256 + threadIdx.x;        // 262144 total
    int lane = gid & 63;
    int n    = (gid >> 6) & 7;
    int kidx = (gid >> 9) & 15;
    int wn   = (gid >> 13) & 3;
    int nb   = gid >> 15;
    int row  = wn * 128 + n * 16 + (lane & 15);      // 0..511 within block
    int col  = kidx * 32 + (lane >> 4) * 8;          // 0..511
    const float* s = W + ((size_t)nb * BOUT + row) * BIN + col;
    f32x4 a = *(const f32x4*)s;
    f32x4 b = *(const f32x4*)(s + 4);
    unsigned long long* d = (unsigned long long*)(pk + (size_t)gid * 8);
    d[0] = pack4(a);
    d[1] = pack4(b);
}

// ---------------- fused 2-layer block-diag MLP ----------------
// wg: 64 batch rows x one full diagonal block (512 cols), both layers.
// 256 threads = 4 waves (1x4 over cols); per wave 64x128 out = 4x8 f32x4 acc.
// ENTIRE x-tile (64x512 bf16 = 64 KB) staged to LDS once up front -> phase 1 is
// barrier-free, identical in shape to phase 2: {LOADQ(L2) -> ds_read -> 32 MFMA}
// streams over 16 half-steps, register-double-buffered W fragments (q0/q1).
// Only THREE barriers per workgroup (post-stage, pre/post h-handoff).
// Hs aliases As (dead after phase 1): pool 64 KB -> 2 blocks/CU.
__global__ __launch_bounds__(256, 2)
void fused_mlp(const float* __restrict__ X,
               const unsigned short* __restrict__ PK1,
               const float* __restrict__ B1,
               const unsigned short* __restrict__ PK2,
               const float* __restrict__ B2,
               float* __restrict__ Out)
{
    __shared__ __align__(16) unsigned char LB[65536];   // [64 rows][1024B] swizzled; As==Hs alias

    const int bid = blockIdx.x;
    const int nb = bid & 7;       // XCD pin: dispatch round-robins bid%8 -> block nb's W resident in one L2
    const int mt = bid >> 3;      // 0..127

    const int t = threadIdx.x;
    const int lane = t & 63;
    const int wn = t >> 6;        // 0..3
    const int l15 = lane & 15;
    const int lhi = lane >> 4;

    const int row0 = mt * 64;
    const int wc0  = nb * 512;

    const unsigned short* s1 = PK1 + (size_t)(nb * 4 + wn) * 65536;
    const unsigned short* s2 = PK2 + (size_t)(nb * 4 + wn) * 65536;

    f32x4 acc[4][8];
    #pragma unroll
    for (int m = 0; m < 4; m++)
        #pragma unroll
        for (int n = 0; n < 8; n++)
            acc[m][n] = (f32x4)(0.f);

    bf16x8 q0[8], q1[8];

#define LOADQ(Q, S, KIDX) { \
    _Pragma("unroll") for (int n = 0; n < 8; n++) \
        Q[n] = *(const bf16x8*)((S) + ((KIDX) * 8 + n) * 512 + lane * 8); }

#define MFMA32(Q, AF) \
    __builtin_amdgcn_s_setprio(1); \
    _Pragma("unroll") for (int m = 0; m < 4; m++) \
        _Pragma("unroll") for (int n = 0; n < 8; n++) \
            acc[m][n] = __builtin_amdgcn_mfma_f32_16x16x32_bf16(AF[m], Q[n], acc[m][n], 0, 0, 0); \
    __builtin_amdgcn_s_setprio(0);

// one half-K-step: prefetch next frag set into QNXT, read af from LDS, 32 MFMA on QCUR
#define HALFSTEP(QCUR, QNXT, SNXT, KNXT, KIDX) { \
    LOADQ(QNXT, SNXT, KNXT); \
    bf16x8 af[4]; \
    const int cb_ = (KIDX) * 64 + lhi * 16; \
    _Pragma("unroll") for (int m = 0; m < 4; m++) { \
        const int r_ = m * 16 + l15; \
        af[m] = *(const bf16x8*)(LB + r_ * 1024 + (cb_ ^ SWZ(r_))); } \
    MFMA32(QCUR, af) }

// final half-step of a phase: no prefetch
#define HALFSTEP_NL(QCUR, KIDX) { \
    bf16x8 af[4]; \
    const int cb_ = (KIDX) * 64 + lhi * 16; \
    _Pragma("unroll") for (int m = 0; m < 4; m++) { \
        const int r_ = m * 16 + l15; \
        af[m] = *(const bf16x8*)(LB + r_ * 1024 + (cb_ ^ SWZ(r_))); } \
    MFMA32(QCUR, af) }

#define BAR() { \
    asm volatile("s_waitcnt lgkmcnt(0)" ::: "memory"); \
    __builtin_amdgcn_s_barrier(); \
    __builtin_amdgcn_sched_barrier(0); }

    // ---- early W1 prefetch: flies during x staging ----
    LOADQ(q0, s1, 0);

    // ---- stage FULL x tile: [64 rows][512 f32] -> bf16, swizzled into LB ----
    // thread t: row sr = t>>2, f32 cols (t&3)*128 .. +127  (16 consecutive 16B slots)
    {
        const int sr = t >> 2;
        const float* xr = X + (size_t)(row0 + sr) * DIM + wc0 + (t & 3) * 128;
        const int j0 = (t & 3) * 16;              // 16B-slot base within row
        #pragma unroll
        for (int i = 0; i < 8; i++) {
            f32x4 a = *(const f32x4*)(xr + i * 16 + 0);
            f32x4 b = *(const f32x4*)(xr + i * 16 + 4);
            f32x4 c = *(const f32x4*)(xr + i * 16 + 8);
            f32x4 d = *(const f32x4*)(xr + i * 16 + 12);
            bf16x8 v0, v1;
            ((unsigned long long*)&v0)[0] = pack4(a);
            ((unsigned long long*)&v0)[1] = pack4(b);
            ((unsigned long long*)&v1)[0] = pack4(c);
            ((unsigned long long*)&v1)[1] = pack4(d);
            *(bf16x8*)(LB + sr * 1024 + (((j0 + 2 * i)     * 16) ^ SWZ(sr))) = v0;
            *(bf16x8*)(LB + sr * 1024 + (((j0 + 2 * i + 1) * 16) ^ SWZ(sr))) = v1;
        }
    }
    BAR();

    // ================= phase 1: acc = x @ W1^T (barrier-free) =================
    #pragma unroll
    for (int kp = 0; kp < 8; kp++) {
        HALFSTEP(q0, q1, s1, 2 * kp + 1, 2 * kp);
        if (kp < 7) { HALFSTEP(q1, q0, s1, 2 * kp + 2, 2 * kp + 1) }
        else        { HALFSTEP(q1, q0, s2, 0,          15)         }   // seed W2 stream
    }

    BAR();   // all As ds_reads retired in every wave -> safe to overwrite with h

    // ---- h = relu(acc + b1) -> LB (same swizzled layout) ----
    #pragma unroll
    for (int n = 0; n < 8; n++) {
        const int c = wn * 128 + n * 16 + l15;
        const float bv = B1[wc0 + c];
        #pragma unroll
        for (int m = 0; m < 4; m++) {
            #pragma unroll
            for (int rr = 0; rr < 4; rr++) {
                float v = acc[m][n][rr] + bv;
                v = v > 0.f ? v : 0.f;
                const int r = m * 16 + lhi * 4 + rr;
                *(unsigned short*)(LB + r * 1024 + ((c * 2) ^ SWZ(r))) = f2bf_rne(v);
            }
        }
    }
    BAR();   // h visible to all waves

    #pragma unroll
    for (int m = 0; m < 4; m++)
        #pragma unroll
        for (int n = 0; n < 8; n++)
            acc[m][n] = (f32x4)(0.f);

    // ================= phase 2: acc = h @ W2^T (barrier-free) =================
    #pragma unroll
    for (int kp = 0; kp < 8; kp++) {
        HALFSTEP(q0, q1, s2, 2 * kp + 1, 2 * kp);
        if (kp < 7) { HALFSTEP(q1, q0, s2, 2 * kp + 2, 2 * kp + 1) }
        else        { HALFSTEP_NL(q1, 15) }
    }

    // ---- epilogue: out = relu(acc + b2), f32 ----
    #pragma unroll
    for (int n = 0; n < 8; n++) {
        const int c = wc0 + wn * 128 + n * 16 + l15;
        const float bv = B2[c];
        #pragma unroll
        for (int m = 0; m < 4; m++) {
            const int rb = row0 + m * 16 + lhi * 4;
            #pragma unroll
            for (int rr = 0; rr < 4; rr++) {
                float v = acc[m][n][rr] + bv;
                Out[(size_t)(rb + rr) * DIM + c] = v > 0.f ? v : 0.f;
            }
        }
    }

#undef LOADQ
#undef MFMA32
#undef HALFSTEP
#undef HALFSTEP_NL
#undef BAR
}

extern "C" void kernel_launch(void* const* d_in, const int* in_sizes, int n_in,
                              void* d_out, int out_size, void* d_ws, size_t ws_size,
                              hipStream_t stream) {
    const float* x  = (const float*)d_in[0];
    const float* W1 = (const float*)d_in[1];
    const float* b1 = (const float*)d_in[2];
    const float* W2 = (const float*)d_in[3];
    const float* b2 = (const float*)d_in[4];
    float* out = (float*)d_out;

    char* ws = (char*)d_ws;
    unsigned short* PK1 = (unsigned short*)ws;                 // 4 MB
    unsigned short* PK2 = (unsigned short*)(ws + (4u << 20));  // 4 MB

    pack_w<<<1024, 256, 0, stream>>>(W1, PK1);
    pack_w<<<1024, 256, 0, stream>>>(W2, PK2);

    const int GRID = NB * (BATCH / 64);     // 1024
    fused_mlp<<<GRID, 256, 0, stream>>>(x, PK1, b1, PK2, b2, out);
}

// Round 7
// 101.460 us; speedup vs baseline: 1.0417x; 1.0334x over previous
//
#include <hip/hip_runtime.h>
#include <hip/hip_bf16.h>

#define NB 8
#define BIN 512
#define BOUT 512
#define BATCH 8192
#define DIM 4096   // NB*BIN

typedef __attribute__((ext_vector_type(8))) short bf16x8;
typedef __attribute__((ext_vector_type(4))) float f32x4;

#define SWZ(r) (((r) & 7) << 4)

__device__ __forceinline__ unsigned short f2bf(float f) {
    // native cast -> v_cvt_pk_bf16_f32 fusion (RNE)
    return __builtin_bit_cast(unsigned short, __float2bfloat16(f));
}

__device__ __forceinline__ unsigned long long pack4(f32x4 f) {
    return (unsigned long long)f2bf(f.x)
         | ((unsigned long long)f2bf(f.y) << 16)
         | ((unsigned long long)f2bf(f.z) << 32)
         | ((unsigned long long)f2bf(f.w) << 48);
}

// ---------------- weight pack: f32 [nb][512][512] -> per-(nb,wn) bf16 fragment streams ----------------
// Stream layout: frag (nb, wn, kidx 0..15, n 0..7): 64 lanes x 16B, contiguous 1KB.
__global__ void pack_w(const float* __restrict__ W, unsigned short* __restrict__ pk) {
    int gid = blockIdx.x * 256 + threadIdx.x;        // 262144 total
    int lane = gid & 63;
    int n    = (gid >> 6) & 7;
    int kidx = (gid >> 9) & 15;
    int wn   = (gid >> 13) & 3;
    int nb   = gid >> 15;
    int row  = wn * 128 + n * 16 + (lane & 15);      // 0..511 within block
    int col  = kidx * 32 + (lane >> 4) * 8;          // 0..511
    const float* s = W + ((size_t)nb * BOUT + row) * BIN + col;
    f32x4 a = *(const f32x4*)s;
    f32x4 b = *(const f32x4*)(s + 4);
    unsigned long long* d = (unsigned long long*)(pk + (size_t)gid * 8);
    d[0] = pack4(a);
    d[1] = pack4(b);
}

// ---------------- fused 2-layer block-diag MLP ----------------
// wg: 64 batch rows x one full diagonal block (512 cols), both layers.
// 256 threads = 4 waves (1x4 over cols); per wave 64x128 out = 4x8 f32x4 acc.
// Full x-tile (64x512 bf16 = 64 KB) staged once; both phases are barrier-free
// {8x global_load(W,L2) -> 4x ds_read(offset-imm) -> 32 MFMA} half-step streams.
// Addressing is VALU-free in steady state: W via incremented pointer + n*1024
// immediates; af via 8 precomputed lane bases (m x kidx-parity) + imm offsets.
__global__ __launch_bounds__(256, 2)
void fused_mlp(const float* __restrict__ X,
               const unsigned short* __restrict__ PK1,
               const float* __restrict__ B1,
               const unsigned short* __restrict__ PK2,
               const float* __restrict__ B2,
               float* __restrict__ Out)
{
    __shared__ __align__(16) unsigned char LB[65536];   // [64 rows][1024B] swizzled; As==Hs alias

    const int bid = blockIdx.x;
    const int nb = bid & 7;       // XCD pin: dispatch round-robins bid%8 -> W resident in one L2
    const int mt = bid >> 3;      // 0..127

    const int t = threadIdx.x;
    const int lane = t & 63;
    const int wn = t >> 6;        // 0..3
    const int l15 = lane & 15;
    const int lhi = lane >> 4;

    const int row0 = mt * 64;
    const int wc0  = nb * 512;

    // per-lane ds_read bases: m (4) x kidx-parity (2).
    // addr(m, kidx) = ab[m][kidx&1] + (kidx>>1)*128  (pure immediate per half-step)
    int ab[4][2];
    #pragma unroll
    for (int m = 0; m < 4; m++) {
        const int r_ = m * 16 + l15;
        #pragma unroll
        for (int par = 0; par < 2; par++)
            ab[m][par] = r_ * 1024 + ((par * 64 + lhi * 16) ^ SWZ(r_));
    }

    const unsigned short* wp1 = PK1 + (size_t)(nb * 4 + wn) * 65536 + lane * 8;
    const unsigned short* wp2 = PK2 + (size_t)(nb * 4 + wn) * 65536 + lane * 8;

    f32x4 acc[4][8];
    #pragma unroll
    for (int m = 0; m < 4; m++)
        #pragma unroll
        for (int n = 0; n < 8; n++)
            acc[m][n] = (f32x4)(0.f);

    bf16x8 q0[8], q1[8];

#define LOADQ(Q, WPTR) { \
    _Pragma("unroll") for (int n = 0; n < 8; n++) \
        Q[n] = *(const bf16x8*)((WPTR) + n * 512); \
    (WPTR) += 4096; }

#define MFMA32(Q, AF) \
    __builtin_amdgcn_s_setprio(1); \
    _Pragma("unroll") for (int m = 0; m < 4; m++) \
        _Pragma("unroll") for (int n = 0; n < 8; n++) \
            acc[m][n] = __builtin_amdgcn_mfma_f32_16x16x32_bf16(AF[m], Q[n], acc[m][n], 0, 0, 0); \
    __builtin_amdgcn_s_setprio(0);

// one half-step: prefetch next frag set (WPTR advances), imm-offset ds_reads, 32 MFMA
#define HSTEP(QC, QN, WPTR, KIDX) { \
    LOADQ(QN, WPTR); \
    bf16x8 af[4]; \
    _Pragma("unroll") for (int m = 0; m < 4; m++) \
        af[m] = *(const bf16x8*)(LB + ab[m][(KIDX) & 1] + ((KIDX) >> 1) * 128); \
    MFMA32(QC, af) }

#define HSTEP_NL(QC, KIDX) { \
    bf16x8 af[4]; \
    _Pragma("unroll") for (int m = 0; m < 4; m++) \
        af[m] = *(const bf16x8*)(LB + ab[m][(KIDX) & 1] + ((KIDX) >> 1) * 128); \
    MFMA32(QC, af) }

#define BAR() { \
    asm volatile("s_waitcnt lgkmcnt(0)" ::: "memory"); \
    __builtin_amdgcn_s_barrier(); \
    __builtin_amdgcn_sched_barrier(0); }

    // ---- early W1 prefetch (kidx 0): flies during x staging ----
    LOADQ(q0, wp1);

    // ---- stage FULL x tile: [64 rows][512 f32] -> bf16, swizzled into LB ----
    {
        const int sr = t >> 2;
        const float* xr = X + (size_t)(row0 + sr) * DIM + wc0 + (t & 3) * 128;
        const int j0 = (t & 3) * 16;              // 16B-slot base within row
        #pragma unroll
        for (int i = 0; i < 8; i++) {
            f32x4 a = *(const f32x4*)(xr + i * 16 + 0);
            f32x4 b = *(const f32x4*)(xr + i * 16 + 4);
            f32x4 c = *(const f32x4*)(xr + i * 16 + 8);
            f32x4 d = *(const f32x4*)(xr + i * 16 + 12);
            bf16x8 v0, v1;
            ((unsigned long long*)&v0)[0] = pack4(a);
            ((unsigned long long*)&v0)[1] = pack4(b);
            ((unsigned long long*)&v1)[0] = pack4(c);
            ((unsigned long long*)&v1)[1] = pack4(d);
            *(bf16x8*)(LB + sr * 1024 + (((j0 + 2 * i)     * 16) ^ SWZ(sr))) = v0;
            *(bf16x8*)(LB + sr * 1024 + (((j0 + 2 * i + 1) * 16) ^ SWZ(sr))) = v1;
        }
    }
    BAR();

    // ================= phase 1: acc = x @ W1^T (barrier-free) =================
    #pragma unroll
    for (int kp = 0; kp < 8; kp++) {
        HSTEP(q0, q1, wp1, 2 * kp);
        if (kp < 7) { HSTEP(q1, q0, wp1, 2 * kp + 1) }
        else        { HSTEP(q1, q0, wp2, 15)         }   // seed W2 stream (kidx 0)
    }

    BAR();   // all As ds_reads retired in every wave -> safe to overwrite with h

    // ---- h = relu(acc + b1) -> LB (same swizzled layout) ----
    #pragma unroll
    for (int n = 0; n < 8; n++) {
        const int c = wn * 128 + n * 16 + l15;
        const float bv = B1[wc0 + c];
        #pragma unroll
        for (int m = 0; m < 4; m++) {
            #pragma unroll
            for (int rr = 0; rr < 4; rr++) {
                float v = acc[m][n][rr] + bv;
                v = v > 0.f ? v : 0.f;
                const int r = m * 16 + lhi * 4 + rr;
                *(unsigned short*)(LB + r * 1024 + ((c * 2) ^ SWZ(r))) = f2bf(v);
            }
        }
    }
    BAR();   // h visible to all waves

    #pragma unroll
    for (int m = 0; m < 4; m++)
        #pragma unroll
        for (int n = 0; n < 8; n++)
            acc[m][n] = (f32x4)(0.f);

    // ================= phase 2: acc = h @ W2^T (barrier-free) =================
    #pragma unroll
    for (int kp = 0; kp < 8; kp++) {
        HSTEP(q0, q1, wp2, 2 * kp);
        if (kp < 7) { HSTEP(q1, q0, wp2, 2 * kp + 1) }
        else        { HSTEP_NL(q1, 15) }
    }

    // ---- epilogue: out = relu(acc + b2), f32 ----
    #pragma unroll
    for (int n = 0; n < 8; n++) {
        const int c = wc0 + wn * 128 + n * 16 + l15;
        const float bv = B2[c];
        #pragma unroll
        for (int m = 0; m < 4; m++) {
            const int rb = row0 + m * 16 + lhi * 4;
            #pragma unroll
            for (int rr = 0; rr < 4; rr++) {
                float v = acc[m][n][rr] + bv;
                Out[(size_t)(rb + rr) * DIM + c] = v > 0.f ? v : 0.f;
            }
        }
    }

#undef LOADQ
#undef MFMA32
#undef HSTEP
#undef HSTEP_NL
#undef BAR
}

extern "C" void kernel_launch(void* const* d_in, const int* in_sizes, int n_in,
                              void* d_out, int out_size, void* d_ws, size_t ws_size,
                              hipStream_t stream) {
    const float* x  = (const float*)d_in[0];
    const float* W1 = (const float*)d_in[1];
    const float* b1 = (const float*)d_in[2];
    const float* W2 = (const float*)d_in[3];
    const float* b2 = (const float*)d_in[4];
    float* out = (float*)d_out;

    char* ws = (char*)d_ws;
    unsigned short* PK1 = (unsigned short*)ws;                 // 4 MB
    unsigned short* PK2 = (unsigned short*)(ws + (4u << 20));  // 4 MB

    pack_w<<<1024, 256, 0, stream>>>(W1, PK1);
    pack_w<<<1024, 256, 0, stream>>>(W2, PK2);

    const int GRID = NB * (BATCH / 64);     // 1024
    fused_mlp<<<GRID, 256, 0, stream>>>(x, PK1, b1, PK2, b2, out);
}